// Round 13
// baseline (343.199 us; speedup 1.0000x reference)
//
#include <hip/hip_runtime.h>
#include <math.h>

#define DD 128
#define CC 40
#define BSH 9          // bucket shift: 512 nodes/bucket
#define BSZ 512
#define EPB 2048       // edges per bin block

typedef __bf16 bf16x8 __attribute__((ext_vector_type(8)));
typedef float f32x4 __attribute__((ext_vector_type(4)));
typedef float f32x2 __attribute__((ext_vector_type(2)));

union BF8 { uint4 q; bf16x8 v; ushort us[8]; };

static __device__ __forceinline__ ushort f2bf(float x) {
    union { float f; unsigned u; } v; v.f = x;
    unsigned r = (v.u + 0x7FFFu + ((v.u >> 16) & 1u)) >> 16;   // RNE
    return (ushort)r;
}
static __device__ __forceinline__ float bf2f(ushort u) {
    union { unsigned u; float f; } v; v.u = ((unsigned)u) << 16;
    return v.f;
}
// per-16-bit unsigned max == bf16 max for non-negative values (post-ReLU)
static __device__ __forceinline__ uint4 bfmax4(uint4 a, uint4 b) {
    union U { uint4 q; ushort us[8]; } x, y;
    x.q = a; y.q = b;
#pragma unroll
    for (int i = 0; i < 8; ++i) x.us[i] = (x.us[i] > y.us[i]) ? x.us[i] : y.us[i];
    return x.q;
}
// byte offset of (row, col_byte) in a 16x256B LDS tile, XOR-swizzled (G4 pattern)
static __device__ __forceinline__ int swz(int row, int colb) {
    return row * 256 + (colb ^ ((row & 7) << 4));
}

// ---- software OCP e4m3 encode (exact, branchless; exponent-mirror x 2^-120) ----
static __device__ __forceinline__ unsigned f2fp8(float x) {
    union { float f; unsigned u; } v; v.f = x * 0x1p-120f;
    unsigned s = (v.u >> 24) & 0x80u;
    unsigned mag = v.u & 0x7fffffffu;
    mag = mag + 0x7ffffu + ((mag >> 20) & 1u);   // RNE at bit 20
    unsigned em = mag >> 20;
    if (em > 0x7eu) em = 0x7eu;                  // clamp to max finite 448
    return s | em;
}
// decode 8 fp8 bytes -> accumulate into acc[0..7]. All decode paths are exact
// (every e4m3 value is f32-representable) -> bit-identical results.
static __device__ __forceinline__ void acc8_fp8(unsigned wx, unsigned wy, float* acc) {
#if __has_builtin(__builtin_amdgcn_cvt_pk_f32_fp8)
    f32x2 p0 = __builtin_amdgcn_cvt_pk_f32_fp8((int)wx, false);
    f32x2 p1 = __builtin_amdgcn_cvt_pk_f32_fp8((int)wx, true);
    f32x2 p2 = __builtin_amdgcn_cvt_pk_f32_fp8((int)wy, false);
    f32x2 p3 = __builtin_amdgcn_cvt_pk_f32_fp8((int)wy, true);
    acc[0] += p0.x; acc[1] += p0.y; acc[2] += p1.x; acc[3] += p1.y;
    acc[4] += p2.x; acc[5] += p2.y; acc[6] += p3.x; acc[7] += p3.y;
#elif __has_builtin(__builtin_amdgcn_cvt_f32_fp8)
    acc[0] += __builtin_amdgcn_cvt_f32_fp8((int)wx, 0);
    acc[1] += __builtin_amdgcn_cvt_f32_fp8((int)wx, 1);
    acc[2] += __builtin_amdgcn_cvt_f32_fp8((int)wx, 2);
    acc[3] += __builtin_amdgcn_cvt_f32_fp8((int)wx, 3);
    acc[4] += __builtin_amdgcn_cvt_f32_fp8((int)wy, 0);
    acc[5] += __builtin_amdgcn_cvt_f32_fp8((int)wy, 1);
    acc[6] += __builtin_amdgcn_cvt_f32_fp8((int)wy, 2);
    acc[7] += __builtin_amdgcn_cvt_f32_fp8((int)wy, 3);
#else
#pragma unroll
    for (int i = 0; i < 4; ++i) {
        unsigned b0 = (wx >> (8 * i)) & 0xffu;
        unsigned b1 = (wy >> (8 * i)) & 0xffu;
        union { unsigned u; float f; } f0, f1;
        f0.u = ((b0 & 0x7fu) << 20) | ((b0 & 0x80u) << 24);
        f1.u = ((b1 & 0x7fu) << 20) | ((b1 & 0x80u) << 24);
        acc[i]     = fmaf(f0.f, 0x1p120f, acc[i]);
        acc[i + 4] = fmaf(f1.f, 0x1p120f, acc[i + 4]);
    }
#endif
}
// decode 16 fp8 bytes (one uint4 = 16 channels) -> acc[0..15]
static __device__ __forceinline__ void acc16_fp8(uint4 w, float* acc) {
    acc8_fp8(w.x, w.y, acc);
    acc8_fp8(w.z, w.w, acc + 8);
}

__device__ __forceinline__ int edge_at_nt(const void* eptr, int is32, long long idx) {
    if (is32) return __builtin_nontemporal_load((const int*)eptr + idx);
    return (int)__builtin_nontemporal_load((const long long*)eptr + idx);
}

// ---------------------------------------------------------------------------
// prep: setup (cursors, deghist, dtype detect) + cvtw + cvtlw fused.
// Wf: MFMA-fragment-ordered conv weights; Wpf: fragment-ordered lin_w (48 cols).
__global__ void prep_kernel(const unsigned* __restrict__ e, int* __restrict__ flag,
                            int* __restrict__ gcursor, int* __restrict__ deghist,
                            int nbk, int bcap,
                            const float* __restrict__ W, ushort* __restrict__ Wf,
                            int totalW,
                            const float* __restrict__ lw, ushort* __restrict__ Wpf) {
    int i = blockIdx.x * 256 + threadIdx.x;
    if (i < nbk) gcursor[i] = i * bcap;
    if (i < 64) deghist[i] = 0;
    if (blockIdx.x == 0 && threadIdx.x < 64) {
        int t = threadIdx.x;
        unsigned nz = 0;
        for (int j = 0; j < 16; ++j) nz |= e[2 * (t * 16 + j) + 1];
        unsigned long long b = __ballot(nz != 0);
        if (t == 0) *flag = (b != 0) ? 1 : 0;
    }
    if (i < totalW) {                                  // cvtw
        int l = i >> 11, r = i & 2047;
        int kc = r >> 9, j = (r >> 6) & 7, lane = r & 63;
        int kgrp = lane >> 4, lrow = lane & 15;
        int col = j * 16 + lrow;
        BF8 o;
#pragma unroll
        for (int q = 0; q < 8; ++q) {
            int k = kc * 32 + kgrp * 8 + q;
            o.us[q] = f2bf(W[((size_t)l * DD + k) * DD + col]);
        }
        *(uint4*)&Wf[((size_t)l * 2048 + r) * 8] = o.q;
    } else if (i < totalW + 12 * 64) {                 // cvtlw
        int tid = i - totalW;
        int f = tid >> 6, lane = tid & 63;
        int kc = f / 3, j = f % 3;
        int kgrp = lane >> 4, lrow = lane & 15;
        int col = j * 16 + lrow;
        BF8 o;
#pragma unroll
        for (int q = 0; q < 8; ++q) {
            int k = kc * 32 + kgrp * 8 + q;
            o.us[q] = (col < CC) ? f2bf(lw[k * CC + col]) : (ushort)0;
        }
        *(uint4*)&Wpf[(size_t)tid * 8] = o.q;
    }
}

// ---------------------------------------------------------------------------
// Bin pass: block = EPB edges; LDS bucket histogram; one global atomicAdd per
// (block,bucket); PACKED 4B pairs (src<<9 | dst_local) in contiguous
// per-bucket runs at STATIC regions [b*bcap, (b+1)*bcap).
__global__ __launch_bounds__(256) void bin_kernel(const void* __restrict__ eptr,
                                                  const int* __restrict__ flag,
                                                  int* __restrict__ gcursor,
                                                  unsigned* __restrict__ bins,
                                                  int E, int nbk, int bcap) {
    __shared__ int lcount[256];
    __shared__ int gbase[256];
    int t = threadIdx.x;
    lcount[t] = 0;
    __syncthreads();
    int is32 = *flag;
    long base = (long)blockIdx.x * EPB;
    const int K = EPB / 256;
    int r[K], c[K], slot[K];
#pragma unroll
    for (int i = 0; i < K; ++i) {
        long e = base + i * 256 + t;
        if (e < E) {
            r[i] = edge_at_nt(eptr, is32, e);
            c[i] = edge_at_nt(eptr, is32, (long long)E + e);
            slot[i] = atomicAdd(&lcount[r[i] >> BSH], 1);
        } else {
            r[i] = -1;
        }
    }
    __syncthreads();
    if (t < nbk && lcount[t] > 0) gbase[t] = atomicAdd(&gcursor[t], lcount[t]);
    __syncthreads();
#pragma unroll
    for (int i = 0; i < K; ++i) {
        if (r[i] >= 0) {
            int b = r[i] >> BSH;
            size_t pos = (size_t)gbase[b] + slot[i];
            if (pos < (size_t)(b + 1) * bcap)            // overflow guard
                bins[pos] = ((unsigned)c[i] << BSH) | (unsigned)(r[i] & (BSZ - 1));
        }
    }
}

// Per-bucket node counting from bins (LDS counters, contiguous cnt writes)
// + fused degree histogram.
__global__ __launch_bounds__(256) void bcount_kernel(const unsigned* __restrict__ bins,
                                                     const int* __restrict__ gcursor,
                                                     int* __restrict__ cnt,
                                                     int* __restrict__ deghist,
                                                     int N, int bcap) {
    __shared__ int lcnt[BSZ];
    __shared__ int ldeg[64];
    int t = threadIdx.x;
    int b = blockIdx.x;
    int node0 = b << BSH;
    for (int i = t; i < BSZ; i += 256) lcnt[i] = 0;
    if (t < 64) ldeg[t] = 0;
    __syncthreads();
    int s = b * bcap;
    int e = gcursor[b];
    if (e > s + bcap) e = s + bcap;
    for (int p = s + t; p < e; p += 256)
        atomicAdd(&lcnt[bins[p] & (BSZ - 1)], 1);
    __syncthreads();
    for (int i = t; i < BSZ; i += 256) {
        int node = node0 + i;
        if (node < N) {
            int c = lcnt[i];
            cnt[node] = c;
            atomicAdd(&ldeg[c < 63 ? c : 63], 1);
        }
    }
    __syncthreads();
    if (t < 64 && ldeg[t] > 0) atomicAdd(&deghist[t], ldeg[t]);
}

// ---------------------------------------------------------------------------
// Hierarchical exclusive scan (1024/block). cnt = in-degree (from bcount).
__global__ __launch_bounds__(1024) void scanA_kernel(int* __restrict__ cnt,
                                                     int* __restrict__ row_ptr,
                                                     float* __restrict__ dinv,
                                                     int* __restrict__ blksum, int N) {
    __shared__ int swave[16];
    int tid = threadIdx.x;
    int lane = tid & 63, wid = tid >> 6;
    int i = blockIdx.x * 1024 + tid;
    int v = (i < N) ? cnt[i] : 0;
    int incl = v;
#pragma unroll
    for (int off = 1; off < 64; off <<= 1) {
        int t = __shfl_up(incl, off);
        if (lane >= off) incl += t;
    }
    if (lane == 63) swave[wid] = incl;
    __syncthreads();
    if (tid < 16) {
        int t = swave[tid];
#pragma unroll
        for (int off = 1; off < 16; off <<= 1) {
            int u = __shfl_up(t, off);
            if (tid >= off) t += u;
        }
        swave[tid] = t;
    }
    __syncthreads();
    int waveoff = (wid == 0) ? 0 : swave[wid - 1];
    if (i < N) {
        row_ptr[i] = waveoff + incl - v;
        dinv[i] = rsqrtf((float)v + 1.0f);
    }
    if (tid == 0) blksum[blockIdx.x] = swave[15];
}

// scanB: scan block sums AND degree histogram -> degcur (exclusive offsets).
__global__ __launch_bounds__(128) void scanB_kernel(int* __restrict__ blksum, int nb,
                                                    const int* __restrict__ deghist,
                                                    int* __restrict__ degcur) {
    __shared__ int s[128];
    int t = threadIdx.x;
    int orig = (t < nb) ? blksum[t] : 0;
    s[t] = orig;
    __syncthreads();
    for (int off = 1; off < 128; off <<= 1) {
        int v = (t >= off) ? s[t - off] : 0;
        __syncthreads();
        s[t] += v;
        __syncthreads();
    }
    if (t < nb) blksum[t] = s[t] - orig;
    if (t < 64) {
        int v = deghist[t];
        int incl = v;
#pragma unroll
        for (int off = 1; off < 64; off <<= 1) {
            int u = __shfl_up(incl, off);
            if ((t & 63) >= off) incl += u;
        }
        degcur[t] = incl - v;
    }
}

// scanC + degree-bucket counting-sort scatter (fused).
__global__ __launch_bounds__(256) void scanCdeg_kernel(int* __restrict__ row_ptr,
                                                       const int* __restrict__ blksum,
                                                       const int* __restrict__ cnt,
                                                       int* __restrict__ degcur,
                                                       int* __restrict__ perm,
                                                       int N, int E) {
    __shared__ int lc[64];
    __shared__ int lbase[64];
    int t = threadIdx.x;
    if (t < 64) lc[t] = 0;
    __syncthreads();
    int i = blockIdx.x * 256 + t;
    if (i < N) row_ptr[i] += blksum[i >> 10];
    if (i == 0) row_ptr[N] = E;
    int deg = -1, slot = 0;
    if (i < N) {
        int c = cnt[i];
        deg = c < 63 ? c : 63;
        slot = atomicAdd(&lc[deg], 1);
    }
    __syncthreads();
    if (t < 64 && lc[t] > 0) lbase[t] = atomicAdd(&degcur[t], lc[t]);
    __syncthreads();
    if (deg >= 0) perm[lbase[deg] + slot] = i;
}

// Bucket scatter: one block per bucket; cursors in LDS; csr writes stay in
// a <=20KB L2-resident slice.
__global__ __launch_bounds__(256) void bscatter_kernel(const unsigned* __restrict__ bins,
                                                       const int* __restrict__ row_ptr,
                                                       const int* __restrict__ gcursor,
                                                       int* __restrict__ csr, int N, int bcap) {
    __shared__ int lcur[BSZ];
    int b = blockIdx.x;
    int node0 = b << BSH;
    for (int i = threadIdx.x; i < BSZ; i += 256) lcur[i] = 0;
    __syncthreads();
    int s = b * bcap;
    int e = gcursor[b];
    if (e > s + bcap) e = s + bcap;
    for (int p = s + threadIdx.x; p < e; p += 256) {
        unsigned pr = bins[p];
        int rl = (int)(pr & (BSZ - 1));
        int c = (int)(pr >> BSH);
        int pos = row_ptr[node0 + rl] + atomicAdd(&lcur[rl], 1);
        csr[pos] = c;
    }
}

// ---------------------------------------------------------------------------
// Y8[N,128](fp8) = dinv[row] * (X[N,128] @ W).
// Block 256 = 4 waves; wave owns 32 rows (2x16) -> 64 MFMA 16x16x32 tiles.
template <int IN32>
__global__ __launch_bounds__(256) void mm_kernel(const void* __restrict__ Xin,
                                                 const ushort* __restrict__ Wf,
                                                 const float* __restrict__ dinv,
                                                 unsigned char* __restrict__ Y8, int N) {
    __shared__ ushort WfS[2048 * 8];   // 32 KB fragment-ordered weights
    __shared__ char slab[4][8192];     // 32 KB per-wave A/epilogue staging
    int t = threadIdx.x;
    int wave = t >> 6, lane = t & 63;
    int wrow0 = blockIdx.x * 128 + wave * 32;
    int lrow = lane & 15, kgrp = lane >> 4;
    char* sw = slab[wave];
    int srow = lane >> 4, scolb = (lane & 15) * 16;

#pragma unroll
    for (int i = 0; i < 8; ++i) {
        int idx = i * 256 + t;         // 0..2047
        *(uint4*)&WfS[(size_t)idx * 8] = *(const uint4*)&Wf[(size_t)idx * 8];
    }

    BF8 a[2][4];
    if (IN32) {
#pragma unroll
        for (int g = 0; g < 2; ++g) {
            int arow = wrow0 + g * 16 + lrow;
#pragma unroll
            for (int kc = 0; kc < 4; ++kc) {
                if (arow < N) {
                    const float* a32 = (const float*)Xin + (size_t)arow * DD + kgrp * 8 + kc * 32;
                    float4 f0 = *(const float4*)a32;
                    float4 f1 = *(const float4*)(a32 + 4);
                    a[g][kc].us[0] = f2bf(f0.x); a[g][kc].us[1] = f2bf(f0.y);
                    a[g][kc].us[2] = f2bf(f0.z); a[g][kc].us[3] = f2bf(f0.w);
                    a[g][kc].us[4] = f2bf(f1.x); a[g][kc].us[5] = f2bf(f1.y);
                    a[g][kc].us[6] = f2bf(f1.z); a[g][kc].us[7] = f2bf(f1.w);
                } else {
                    a[g][kc].q = make_uint4(0, 0, 0, 0);
                }
            }
        }
    } else {
        const ushort* Xb = (const ushort*)Xin;   // NPAD2-padded bf16
        size_t tb = (size_t)wrow0 * DD;
#pragma unroll
        for (int i = 0; i < 8; ++i) {
            uint4 v = *(const uint4*)&Xb[tb + i * 512 + lane * 8];
            int row = i * 4 + srow;              // 0..31
            *(uint4*)(sw + ((row & 16) ? 4096 : 0) + swz(row & 15, scolb)) = v;
        }
#pragma unroll
        for (int g = 0; g < 2; ++g)
#pragma unroll
            for (int kc = 0; kc < 4; ++kc)
                a[g][kc].q = *(const uint4*)(sw + g * 4096 + swz(lrow, kgrp * 16 + kc * 64));
    }
    __syncthreads();   // WfS ready

    f32x4 acc[2][8];
#pragma unroll
    for (int g = 0; g < 2; ++g)
#pragma unroll
        for (int j = 0; j < 8; ++j) acc[g][j] = (f32x4){0.f, 0.f, 0.f, 0.f};

#pragma unroll
    for (int kc = 0; kc < 4; ++kc) {
#pragma unroll
        for (int j = 0; j < 8; ++j) {
            BF8 b;
            b.q = *(const uint4*)&WfS[(size_t)((kc * 8 + j) * 64 + lane) * 8];
            acc[0][j] = __builtin_amdgcn_mfma_f32_16x16x32_bf16(a[0][kc].v, b.v, acc[0][j], 0, 0, 0);
            acc[1][j] = __builtin_amdgcn_mfma_f32_16x16x32_bf16(a[1][kc].v, b.v, acc[1][j], 0, 0, 0);
        }
    }

    float dv[2][4];
#pragma unroll
    for (int g = 0; g < 2; ++g)
#pragma unroll
        for (int r = 0; r < 4; ++r) {
            int row = wrow0 + g * 16 + kgrp * 4 + r;
            dv[g][r] = dinv[row < N ? row : (N - 1)];
        }

#pragma unroll
    for (int g = 0; g < 2; ++g) {
        char* sg = sw + g * 4096;
#pragma unroll
        for (int j = 0; j < 8; ++j) {
            int colb = (j * 16 + lrow) * 2;
#pragma unroll
            for (int r = 0; r < 4; ++r)
                *(ushort*)(sg + swz(kgrp * 4 + r, colb)) = f2bf(acc[g][j][r] * dv[g][r]);
        }
        size_t tb8 = (size_t)(wrow0 + g * 16) * DD;   // fp8: 128 B per row
#pragma unroll
        for (int i = 0; i < 4; ++i) {
            int row = i * 4 + srow;
            BF8 o;
            o.q = *(const uint4*)(sg + swz(row, scolb));
            uint2 w;
            w.x = f2fp8(bf2f(o.us[0])) | (f2fp8(bf2f(o.us[1])) << 8) |
                  (f2fp8(bf2f(o.us[2])) << 16) | (f2fp8(bf2f(o.us[3])) << 24);
            w.y = f2fp8(bf2f(o.us[4])) | (f2fp8(bf2f(o.us[5])) << 8) |
                  (f2fp8(bf2f(o.us[6])) << 16) | (f2fp8(bf2f(o.us[7])) << 24);
            int grow = wrow0 + g * 16 + row;
            if (grow < N) *(uint2*)&Y8[tb8 + i * 512 + lane * 8] = w;
        }
    }
}

// ---------------------------------------------------------------------------
// Fused CSR gather-agg (+self fold) + bias + BN + ReLU on pre-scaled fp8 hs.
// Degree-sorted (perm); 8 lanes/node (16B = full half-row per lane) -> each
// wave-instruction issues 8 random 128B row segments. unroll-4, acc-set
// rotation (p mod 4) identical to prior rounds -> bit-identical numerics.
__global__ __launch_bounds__(256) void agg_kernel(
    const unsigned char* __restrict__ hs8, const int* __restrict__ row_ptr,
    const int* __restrict__ csr, const float* __restrict__ dinv,
    const int* __restrict__ perm,
    const float* __restrict__ bias, const float* __restrict__ gamma,
    const float* __restrict__ beta, const float* __restrict__ mean,
    const float* __restrict__ var, ushort* __restrict__ hout, int N) {
    int gid0 = (blockIdx.x * blockDim.x + threadIdx.x) >> 3;
    if (gid0 >= N) return;
    int gid = perm[gid0];
    int lane = threadIdx.x & 7;
    int c8 = lane * 16;                // byte (= channel) offset, 16 ch/lane

    float acc0[16], acc1[16], acc2[16], acc3[16];
#pragma unroll
    for (int i = 0; i < 16; ++i) { acc0[i] = 0.f; acc1[i] = 0.f; acc2[i] = 0.f; acc3[i] = 0.f; }
    acc16_fp8(*(const uint4*)&hs8[(size_t)gid * DD + c8], acc0);   // self

    int s = row_ptr[gid], e = row_ptr[gid + 1];
    int p = s;
    for (; p + 4 <= e; p += 4) {
        int s0 = csr[p], s1 = csr[p + 1], s2 = csr[p + 2], s3 = csr[p + 3];
        uint4 r0 = *(const uint4*)&hs8[(size_t)s0 * DD + c8];
        uint4 r1 = *(const uint4*)&hs8[(size_t)s1 * DD + c8];
        uint4 r2 = *(const uint4*)&hs8[(size_t)s2 * DD + c8];
        uint4 r3 = *(const uint4*)&hs8[(size_t)s3 * DD + c8];
        acc16_fp8(r0, acc0);
        acc16_fp8(r1, acc1);
        acc16_fp8(r2, acc2);
        acc16_fp8(r3, acc3);
    }
    for (; p < e; ++p) {
        int s0 = csr[p];
        acc16_fp8(*(const uint4*)&hs8[(size_t)s0 * DD + c8], acc0);
    }
#pragma unroll
    for (int i = 0; i < 16; ++i) acc0[i] += (acc1[i] + acc2[i]) + acc3[i];

    float di = dinv[gid];
    int c = lane * 16;

    float bb[16], gg[16], be[16], mm[16], vv[16];
#pragma unroll
    for (int q = 0; q < 4; ++q) {
        *(float4*)&bb[q * 4] = *(const float4*)&bias[c + q * 4];
        *(float4*)&gg[q * 4] = *(const float4*)&gamma[c + q * 4];
        *(float4*)&be[q * 4] = *(const float4*)&beta[c + q * 4];
        *(float4*)&mm[q * 4] = *(const float4*)&mean[c + q * 4];
        *(float4*)&vv[q * 4] = *(const float4*)&var[c + q * 4];
    }

    ushort o[16];
#pragma unroll
    for (int i = 0; i < 16; ++i) {
        float h = fmaf(di, acc0[i], bb[i]);
        float y = fmaxf(gg[i] * (h - mm[i]) * rsqrtf(vv[i] + 1e-5f) + be[i], 0.f);
        o[i] = f2bf(y);
    }
    *(uint4*)&hout[(size_t)gid * DD + c]     = *(uint4*)&o[0];
    *(uint4*)&hout[(size_t)gid * DD + c + 8] = *(uint4*)&o[8];
}

// ---------------------------------------------------------------------------
// out = log_softmax( (max_l h_l) @ lin_w + lin_b ). MFMA.
__global__ __launch_bounds__(256) void final_kernel(const ushort* __restrict__ hall,
                                                    size_t hstride, int L,
                                                    const ushort* __restrict__ Wpf,
                                                    const float* __restrict__ lb,
                                                    float* __restrict__ out, int N) {
    __shared__ char slab[4][4096];
    int wave = threadIdx.x >> 6, lane = threadIdx.x & 63;
    int row0 = blockIdx.x * 64 + wave * 16;
    int lrow = lane & 15, kgrp = lane >> 4;
    char* sw = slab[wave];
    size_t tbase = (size_t)row0 * DD;
    int srow = lane >> 4;
    int scolb = (lane & 15) * 16;

#pragma unroll
    for (int i = 0; i < 4; ++i) {
        const ushort* pp = &hall[tbase + i * 512 + lane * 8];
        uint4 m = *(const uint4*)pp;
        for (int l = 1; l < L; ++l)
            m = bfmax4(m, *(const uint4*)(pp + (size_t)l * hstride));
        int row = i * 4 + srow;
        *(uint4*)(sw + swz(row, scolb)) = m;
    }

    BF8 a[4];
#pragma unroll
    for (int kc = 0; kc < 4; ++kc)
        a[kc].q = *(const uint4*)(sw + swz(lrow, kgrp * 16 + kc * 64));

    f32x4 acc[3];
#pragma unroll
    for (int j = 0; j < 3; ++j) acc[j] = (f32x4){0.f, 0.f, 0.f, 0.f};
#pragma unroll
    for (int kc = 0; kc < 4; ++kc) {
#pragma unroll
        for (int j = 0; j < 3; ++j) {
            BF8 b;
            b.q = *(const uint4*)&Wpf[(size_t)((kc * 3 + j) * 64 + lane) * 8];
            acc[j] = __builtin_amdgcn_mfma_f32_16x16x32_bf16(a[kc].v, b.v, acc[j], 0, 0, 0);
        }
    }

    float lbv[3];
#pragma unroll
    for (int j = 0; j < 3; ++j) {
        int col = j * 16 + lrow;
        lbv[j] = (col < CC) ? lb[col] : 0.f;
    }
#pragma unroll
    for (int r = 0; r < 4; ++r) {
        int node = row0 + kgrp * 4 + r;
        float lg[3];
        float m = -1e30f;
#pragma unroll
        for (int j = 0; j < 3; ++j) {
            int col = j * 16 + lrow;
            float v = (col < CC) ? (acc[j][r] + lbv[j]) : -1e30f;
            lg[j] = v;
            m = fmaxf(m, v);
        }
        m = fmaxf(m, __shfl_xor(m, 1));
        m = fmaxf(m, __shfl_xor(m, 2));
        m = fmaxf(m, __shfl_xor(m, 4));
        m = fmaxf(m, __shfl_xor(m, 8));
        float s = 0.f;
#pragma unroll
        for (int j = 0; j < 3; ++j) {
            int col = j * 16 + lrow;
            if (col < CC) s += expf(lg[j] - m);
        }
        s += __shfl_xor(s, 1);
        s += __shfl_xor(s, 2);
        s += __shfl_xor(s, 4);
        s += __shfl_xor(s, 8);
        float lgs = logf(s);
        if (node < N) {
#pragma unroll
            for (int j = 0; j < 3; ++j) {
                int col = j * 16 + lrow;
                if (col < CC) out[(size_t)node * CC + col] = lg[j] - m - lgs;
            }
        }
    }
}

// ---------------------------------------------------------------------------
extern "C" void kernel_launch(void* const* d_in, const int* in_sizes, int n_in,
                              void* d_out, int out_size, void* d_ws, size_t ws_size,
                              hipStream_t stream) {
    const float* x      = (const float*)d_in[0];
    const void*  eidx   = d_in[1];
    const float* conv_w = (const float*)d_in[2];
    const float* conv_b = (const float*)d_in[3];
    const float* gamma  = (const float*)d_in[4];
    const float* beta   = (const float*)d_in[5];
    const float* mean   = (const float*)d_in[6];
    const float* var    = (const float*)d_in[7];
    const float* lin_w  = (const float*)d_in[8];
    const float* lin_b  = (const float*)d_in[9];
    float* out = (float*)d_out;

    const int N = in_sizes[0] / DD;          // 100000
    const int E = in_sizes[1] / 2;           // 800000
    const int L = in_sizes[3] / DD;          // 5
    const int NPAD2 = (N + 127) & ~127;      // 100096 (mm: 128 rows/block)
    const size_t hstride = (size_t)NPAD2 * DD;
    const int NB = (N + 1023) / 1024;        // scanA blocks
    const int nbk = (N + BSZ - 1) >> BSH;    // buckets (196)
    const int nbb = (E + EPB - 1) / EPB;     // bin blocks
    const int bcap = 2 * ((E + nbk - 1) / nbk) + 512;   // static bucket capacity
    const int totalW = L * 2048;
    const int prepn = totalW + 12 * 64;      // prep thread count (>= nbk, 64)

    char* p = (char*)d_ws;
    auto alloc = [&](size_t bytes) -> char* {
        char* r = p;
        p += (bytes + 255) & ~(size_t)255;
        return r;
    };
    unsigned char* xs8 = (unsigned char*)alloc(hstride);     // fp8 hs (per layer)
    ushort* hall   = (ushort*)alloc((size_t)L * hstride * 2);
    ushort* Wf     = (ushort*)alloc((size_t)L * DD * DD * 2);
    ushort* Wpf    = (ushort*)alloc((size_t)12 * 64 * 8 * 2);
    float*  dinv   = (float*)alloc((size_t)N * 4);
    int*    row_ptr= (int*)alloc((size_t)(N + 1) * 4);
    int*    cnt    = (int*)alloc((size_t)N * 4);
    int*    csr    = (int*)alloc((size_t)E * 4);
    int*    perm   = (int*)alloc((size_t)N * 4);
    unsigned* bins = (unsigned*)alloc((size_t)nbk * bcap * 4);
    int*    gcursor= (int*)alloc((size_t)nbk * 4);
    int*    blksum = (int*)alloc(128 * 4);
    int*    deghist= (int*)alloc(64 * 4);
    int*    degcur = (int*)alloc(64 * 4);
    int*    flag   = (int*)alloc(4);

    prep_kernel<<<(prepn + 255) / 256, 256, 0, stream>>>(
        (const unsigned*)eidx, flag, gcursor, deghist, nbk, bcap,
        conv_w, Wf, totalW, lin_w, Wpf);
    bin_kernel<<<nbb, 256, 0, stream>>>(eidx, flag, gcursor, bins, E, nbk, bcap);
    bcount_kernel<<<nbk, 256, 0, stream>>>(bins, gcursor, cnt, deghist, N, bcap);
    scanA_kernel<<<NB, 1024, 0, stream>>>(cnt, row_ptr, dinv, blksum, N);
    scanB_kernel<<<1, 128, 0, stream>>>(blksum, NB, deghist, degcur);
    scanCdeg_kernel<<<(N + 255) / 256, 256, 0, stream>>>(row_ptr, blksum, cnt, degcur, perm, N, E);
    bscatter_kernel<<<nbk, 256, 0, stream>>>(bins, row_ptr, gcursor, csr, N, bcap);

    for (int l = 0; l < L; ++l) {
        const ushort* Wl = Wf + (size_t)l * DD * DD;
        if (l == 0)
            mm_kernel<1><<<NPAD2 / 128, 256, 0, stream>>>(x, Wl, dinv, xs8, N);
        else
            mm_kernel<0><<<NPAD2 / 128, 256, 0, stream>>>(hall + (size_t)(l - 1) * hstride, Wl, dinv, xs8, N);
        ushort* hl = hall + (size_t)l * hstride;
        agg_kernel<<<(int)(((size_t)N * 8 + 255) / 256), 256, 0, stream>>>(
            xs8, row_ptr, csr, dinv, perm,
            conv_b + (size_t)l * DD, gamma + (size_t)l * DD, beta + (size_t)l * DD,
            mean + (size_t)l * DD, var + (size_t)l * DD, hl, N);
    }
    final_kernel<<<(N + 63) / 64, 256, 0, stream>>>(hall, hstride, L, Wpf, lin_b, out, N);
}

// Round 14
// 307.370 us; speedup vs baseline: 1.1166x; 1.1166x over previous
//
#include <hip/hip_runtime.h>
#include <math.h>

#define DD 128
#define CC 40
#define BSH 9          // bucket shift: 512 nodes/bucket
#define BSZ 512
#define EPB 2048       // edges per bin block

typedef __bf16 bf16x8 __attribute__((ext_vector_type(8)));
typedef float f32x4 __attribute__((ext_vector_type(4)));
typedef float f32x2 __attribute__((ext_vector_type(2)));

union BF8 { uint4 q; bf16x8 v; ushort us[8]; };

static __device__ __forceinline__ ushort f2bf(float x) {
    union { float f; unsigned u; } v; v.f = x;
    unsigned r = (v.u + 0x7FFFu + ((v.u >> 16) & 1u)) >> 16;   // RNE
    return (ushort)r;
}
static __device__ __forceinline__ float bf2f(ushort u) {
    union { unsigned u; float f; } v; v.u = ((unsigned)u) << 16;
    return v.f;
}
// per-16-bit unsigned max == bf16 max for non-negative values (post-ReLU)
static __device__ __forceinline__ uint4 bfmax4(uint4 a, uint4 b) {
    union U { uint4 q; ushort us[8]; } x, y;
    x.q = a; y.q = b;
#pragma unroll
    for (int i = 0; i < 8; ++i) x.us[i] = (x.us[i] > y.us[i]) ? x.us[i] : y.us[i];
    return x.q;
}
// byte offset of (row, col_byte) in a 16x256B LDS tile, XOR-swizzled (G4 pattern)
static __device__ __forceinline__ int swz(int row, int colb) {
    return row * 256 + (colb ^ ((row & 7) << 4));
}

// ---- software OCP e4m3 encode (exact, branchless; exponent-mirror x 2^-120) ----
static __device__ __forceinline__ unsigned f2fp8(float x) {
    union { float f; unsigned u; } v; v.f = x * 0x1p-120f;
    unsigned s = (v.u >> 24) & 0x80u;
    unsigned mag = v.u & 0x7fffffffu;
    mag = mag + 0x7ffffu + ((mag >> 20) & 1u);   // RNE at bit 20
    unsigned em = mag >> 20;
    if (em > 0x7eu) em = 0x7eu;                  // clamp to max finite 448
    return s | em;
}
// decode 8 fp8 bytes -> accumulate into acc[0..7]. All decode paths are exact
// (every e4m3 value is f32-representable) -> bit-identical results.
static __device__ __forceinline__ void acc8_fp8(unsigned wx, unsigned wy, float* acc) {
#if __has_builtin(__builtin_amdgcn_cvt_pk_f32_fp8)
    f32x2 p0 = __builtin_amdgcn_cvt_pk_f32_fp8((int)wx, false);
    f32x2 p1 = __builtin_amdgcn_cvt_pk_f32_fp8((int)wx, true);
    f32x2 p2 = __builtin_amdgcn_cvt_pk_f32_fp8((int)wy, false);
    f32x2 p3 = __builtin_amdgcn_cvt_pk_f32_fp8((int)wy, true);
    acc[0] += p0.x; acc[1] += p0.y; acc[2] += p1.x; acc[3] += p1.y;
    acc[4] += p2.x; acc[5] += p2.y; acc[6] += p3.x; acc[7] += p3.y;
#elif __has_builtin(__builtin_amdgcn_cvt_f32_fp8)
    acc[0] += __builtin_amdgcn_cvt_f32_fp8((int)wx, 0);
    acc[1] += __builtin_amdgcn_cvt_f32_fp8((int)wx, 1);
    acc[2] += __builtin_amdgcn_cvt_f32_fp8((int)wx, 2);
    acc[3] += __builtin_amdgcn_cvt_f32_fp8((int)wx, 3);
    acc[4] += __builtin_amdgcn_cvt_f32_fp8((int)wy, 0);
    acc[5] += __builtin_amdgcn_cvt_f32_fp8((int)wy, 1);
    acc[6] += __builtin_amdgcn_cvt_f32_fp8((int)wy, 2);
    acc[7] += __builtin_amdgcn_cvt_f32_fp8((int)wy, 3);
#else
#pragma unroll
    for (int i = 0; i < 4; ++i) {
        unsigned b0 = (wx >> (8 * i)) & 0xffu;
        unsigned b1 = (wy >> (8 * i)) & 0xffu;
        union { unsigned u; float f; } f0, f1;
        f0.u = ((b0 & 0x7fu) << 20) | ((b0 & 0x80u) << 24);
        f1.u = ((b1 & 0x7fu) << 20) | ((b1 & 0x80u) << 24);
        acc[i]     = fmaf(f0.f, 0x1p120f, acc[i]);
        acc[i + 4] = fmaf(f1.f, 0x1p120f, acc[i + 4]);
    }
#endif
}

__device__ __forceinline__ int edge_at_nt(const void* eptr, int is32, long long idx) {
    if (is32) return __builtin_nontemporal_load((const int*)eptr + idx);
    return (int)__builtin_nontemporal_load((const long long*)eptr + idx);
}

// ---------------------------------------------------------------------------
// prep: setup (cursors, deghist, dtype detect) + cvtw + cvtlw fused.
__global__ void prep_kernel(const unsigned* __restrict__ e, int* __restrict__ flag,
                            int* __restrict__ gcursor, int* __restrict__ deghist,
                            int nbk, int bcap,
                            const float* __restrict__ W, ushort* __restrict__ Wf,
                            int totalW,
                            const float* __restrict__ lw, ushort* __restrict__ Wpf) {
    int i = blockIdx.x * 256 + threadIdx.x;
    if (i < nbk) gcursor[i] = i * bcap;
    if (i < 64) deghist[i] = 0;
    if (blockIdx.x == 0 && threadIdx.x < 64) {
        int t = threadIdx.x;
        unsigned nz = 0;
        for (int j = 0; j < 16; ++j) nz |= e[2 * (t * 16 + j) + 1];
        unsigned long long b = __ballot(nz != 0);
        if (t == 0) *flag = (b != 0) ? 1 : 0;
    }
    if (i < totalW) {                                  // cvtw
        int l = i >> 11, r = i & 2047;
        int kc = r >> 9, j = (r >> 6) & 7, lane = r & 63;
        int kgrp = lane >> 4, lrow = lane & 15;
        int col = j * 16 + lrow;
        BF8 o;
#pragma unroll
        for (int q = 0; q < 8; ++q) {
            int k = kc * 32 + kgrp * 8 + q;
            o.us[q] = f2bf(W[((size_t)l * DD + k) * DD + col]);
        }
        *(uint4*)&Wf[((size_t)l * 2048 + r) * 8] = o.q;
    } else if (i < totalW + 12 * 64) {                 // cvtlw
        int tid = i - totalW;
        int f = tid >> 6, lane = tid & 63;
        int kc = f / 3, j = f % 3;
        int kgrp = lane >> 4, lrow = lane & 15;
        int col = j * 16 + lrow;
        BF8 o;
#pragma unroll
        for (int q = 0; q < 8; ++q) {
            int k = kc * 32 + kgrp * 8 + q;
            o.us[q] = (col < CC) ? f2bf(lw[k * CC + col]) : (ushort)0;
        }
        *(uint4*)&Wpf[(size_t)tid * 8] = o.q;
    }
}

// ---------------------------------------------------------------------------
// Bin pass: block = EPB edges; LDS bucket histogram; one global atomicAdd per
// (block,bucket); PACKED 4B pairs (src<<9 | dst_local) in contiguous
// per-bucket runs at STATIC regions [b*bcap, (b+1)*bcap).
__global__ __launch_bounds__(256) void bin_kernel(const void* __restrict__ eptr,
                                                  const int* __restrict__ flag,
                                                  int* __restrict__ gcursor,
                                                  unsigned* __restrict__ bins,
                                                  int E, int nbk, int bcap) {
    __shared__ int lcount[256];
    __shared__ int gbase[256];
    int t = threadIdx.x;
    lcount[t] = 0;
    __syncthreads();
    int is32 = *flag;
    long base = (long)blockIdx.x * EPB;
    const int K = EPB / 256;
    int r[K], c[K], slot[K];
#pragma unroll
    for (int i = 0; i < K; ++i) {
        long e = base + i * 256 + t;
        if (e < E) {
            r[i] = edge_at_nt(eptr, is32, e);
            c[i] = edge_at_nt(eptr, is32, (long long)E + e);
            slot[i] = atomicAdd(&lcount[r[i] >> BSH], 1);
        } else {
            r[i] = -1;
        }
    }
    __syncthreads();
    if (t < nbk && lcount[t] > 0) gbase[t] = atomicAdd(&gcursor[t], lcount[t]);
    __syncthreads();
#pragma unroll
    for (int i = 0; i < K; ++i) {
        if (r[i] >= 0) {
            int b = r[i] >> BSH;
            size_t pos = (size_t)gbase[b] + slot[i];
            if (pos < (size_t)(b + 1) * bcap)            // overflow guard
                bins[pos] = ((unsigned)c[i] << BSH) | (unsigned)(r[i] & (BSZ - 1));
        }
    }
}

// Per-bucket node counting from bins (LDS counters, contiguous cnt writes)
// + fused degree histogram.
__global__ __launch_bounds__(256) void bcount_kernel(const unsigned* __restrict__ bins,
                                                     const int* __restrict__ gcursor,
                                                     int* __restrict__ cnt,
                                                     int* __restrict__ deghist,
                                                     int N, int bcap) {
    __shared__ int lcnt[BSZ];
    __shared__ int ldeg[64];
    int t = threadIdx.x;
    int b = blockIdx.x;
    int node0 = b << BSH;
    for (int i = t; i < BSZ; i += 256) lcnt[i] = 0;
    if (t < 64) ldeg[t] = 0;
    __syncthreads();
    int s = b * bcap;
    int e = gcursor[b];
    if (e > s + bcap) e = s + bcap;
    for (int p = s + t; p < e; p += 256)
        atomicAdd(&lcnt[bins[p] & (BSZ - 1)], 1);
    __syncthreads();
    for (int i = t; i < BSZ; i += 256) {
        int node = node0 + i;
        if (node < N) {
            int c = lcnt[i];
            cnt[node] = c;
            atomicAdd(&ldeg[c < 63 ? c : 63], 1);
        }
    }
    __syncthreads();
    if (t < 64 && ldeg[t] > 0) atomicAdd(&deghist[t], ldeg[t]);
}

// ---------------------------------------------------------------------------
// Hierarchical exclusive scan (1024/block). cnt = in-degree (from bcount).
__global__ __launch_bounds__(1024) void scanA_kernel(int* __restrict__ cnt,
                                                     int* __restrict__ row_ptr,
                                                     float* __restrict__ dinv,
                                                     int* __restrict__ blksum, int N) {
    __shared__ int swave[16];
    int tid = threadIdx.x;
    int lane = tid & 63, wid = tid >> 6;
    int i = blockIdx.x * 1024 + tid;
    int v = (i < N) ? cnt[i] : 0;
    int incl = v;
#pragma unroll
    for (int off = 1; off < 64; off <<= 1) {
        int t = __shfl_up(incl, off);
        if (lane >= off) incl += t;
    }
    if (lane == 63) swave[wid] = incl;
    __syncthreads();
    if (tid < 16) {
        int t = swave[tid];
#pragma unroll
        for (int off = 1; off < 16; off <<= 1) {
            int u = __shfl_up(t, off);
            if (tid >= off) t += u;
        }
        swave[tid] = t;
    }
    __syncthreads();
    int waveoff = (wid == 0) ? 0 : swave[wid - 1];
    if (i < N) {
        row_ptr[i] = waveoff + incl - v;
        dinv[i] = rsqrtf((float)v + 1.0f);
    }
    if (tid == 0) blksum[blockIdx.x] = swave[15];
}

// scanB: scan block sums AND degree histogram -> degcur (exclusive offsets).
__global__ __launch_bounds__(128) void scanB_kernel(int* __restrict__ blksum, int nb,
                                                    const int* __restrict__ deghist,
                                                    int* __restrict__ degcur) {
    __shared__ int s[128];
    int t = threadIdx.x;
    int orig = (t < nb) ? blksum[t] : 0;
    s[t] = orig;
    __syncthreads();
    for (int off = 1; off < 128; off <<= 1) {
        int v = (t >= off) ? s[t - off] : 0;
        __syncthreads();
        s[t] += v;
        __syncthreads();
    }
    if (t < nb) blksum[t] = s[t] - orig;
    if (t < 64) {
        int v = deghist[t];
        int incl = v;
#pragma unroll
        for (int off = 1; off < 64; off <<= 1) {
            int u = __shfl_up(incl, off);
            if ((t & 63) >= off) incl += u;
        }
        degcur[t] = incl - v;
    }
}

// scanC + degree-bucket counting-sort scatter (fused).
__global__ __launch_bounds__(256) void scanCdeg_kernel(int* __restrict__ row_ptr,
                                                       const int* __restrict__ blksum,
                                                       const int* __restrict__ cnt,
                                                       int* __restrict__ degcur,
                                                       int* __restrict__ perm,
                                                       int N, int E) {
    __shared__ int lc[64];
    __shared__ int lbase[64];
    int t = threadIdx.x;
    if (t < 64) lc[t] = 0;
    __syncthreads();
    int i = blockIdx.x * 256 + t;
    if (i < N) row_ptr[i] += blksum[i >> 10];
    if (i == 0) row_ptr[N] = E;
    int deg = -1, slot = 0;
    if (i < N) {
        int c = cnt[i];
        deg = c < 63 ? c : 63;
        slot = atomicAdd(&lc[deg], 1);
    }
    __syncthreads();
    if (t < 64 && lc[t] > 0) lbase[t] = atomicAdd(&degcur[t], lc[t]);
    __syncthreads();
    if (deg >= 0) perm[lbase[deg] + slot] = i;
}

// Bucket scatter: one block per bucket; cursors in LDS; csr writes stay in
// a <=20KB L2-resident slice.
__global__ __launch_bounds__(256) void bscatter_kernel(const unsigned* __restrict__ bins,
                                                       const int* __restrict__ row_ptr,
                                                       const int* __restrict__ gcursor,
                                                       int* __restrict__ csr, int N, int bcap) {
    __shared__ int lcur[BSZ];
    int b = blockIdx.x;
    int node0 = b << BSH;
    for (int i = threadIdx.x; i < BSZ; i += 256) lcur[i] = 0;
    __syncthreads();
    int s = b * bcap;
    int e = gcursor[b];
    if (e > s + bcap) e = s + bcap;
    for (int p = s + threadIdx.x; p < e; p += 256) {
        unsigned pr = bins[p];
        int rl = (int)(pr & (BSZ - 1));
        int c = (int)(pr >> BSH);
        int pos = row_ptr[node0 + rl] + atomicAdd(&lcur[rl], 1);
        csr[pos] = c;
    }
}

// ---------------------------------------------------------------------------
// Y8[N,128](fp8) = dinv[row] * (X[N,128] @ W).
// Block 256 = 4 waves; wave owns 32 rows (2x16) -> 64 MFMA 16x16x32 tiles.
template <int IN32>
__global__ __launch_bounds__(256) void mm_kernel(const void* __restrict__ Xin,
                                                 const ushort* __restrict__ Wf,
                                                 const float* __restrict__ dinv,
                                                 unsigned char* __restrict__ Y8, int N) {
    __shared__ ushort WfS[2048 * 8];   // 32 KB fragment-ordered weights
    __shared__ char slab[4][8192];     // 32 KB per-wave A/epilogue staging
    int t = threadIdx.x;
    int wave = t >> 6, lane = t & 63;
    int wrow0 = blockIdx.x * 128 + wave * 32;
    int lrow = lane & 15, kgrp = lane >> 4;
    char* sw = slab[wave];
    int srow = lane >> 4, scolb = (lane & 15) * 16;

#pragma unroll
    for (int i = 0; i < 8; ++i) {
        int idx = i * 256 + t;         // 0..2047
        *(uint4*)&WfS[(size_t)idx * 8] = *(const uint4*)&Wf[(size_t)idx * 8];
    }

    BF8 a[2][4];
    if (IN32) {
#pragma unroll
        for (int g = 0; g < 2; ++g) {
            int arow = wrow0 + g * 16 + lrow;
#pragma unroll
            for (int kc = 0; kc < 4; ++kc) {
                if (arow < N) {
                    const float* a32 = (const float*)Xin + (size_t)arow * DD + kgrp * 8 + kc * 32;
                    float4 f0 = *(const float4*)a32;
                    float4 f1 = *(const float4*)(a32 + 4);
                    a[g][kc].us[0] = f2bf(f0.x); a[g][kc].us[1] = f2bf(f0.y);
                    a[g][kc].us[2] = f2bf(f0.z); a[g][kc].us[3] = f2bf(f0.w);
                    a[g][kc].us[4] = f2bf(f1.x); a[g][kc].us[5] = f2bf(f1.y);
                    a[g][kc].us[6] = f2bf(f1.z); a[g][kc].us[7] = f2bf(f1.w);
                } else {
                    a[g][kc].q = make_uint4(0, 0, 0, 0);
                }
            }
        }
    } else {
        const ushort* Xb = (const ushort*)Xin;   // NPAD2-padded bf16
        size_t tb = (size_t)wrow0 * DD;
#pragma unroll
        for (int i = 0; i < 8; ++i) {
            uint4 v = *(const uint4*)&Xb[tb + i * 512 + lane * 8];
            int row = i * 4 + srow;              // 0..31
            *(uint4*)(sw + ((row & 16) ? 4096 : 0) + swz(row & 15, scolb)) = v;
        }
#pragma unroll
        for (int g = 0; g < 2; ++g)
#pragma unroll
            for (int kc = 0; kc < 4; ++kc)
                a[g][kc].q = *(const uint4*)(sw + g * 4096 + swz(lrow, kgrp * 16 + kc * 64));
    }
    __syncthreads();   // WfS ready

    f32x4 acc[2][8];
#pragma unroll
    for (int g = 0; g < 2; ++g)
#pragma unroll
        for (int j = 0; j < 8; ++j) acc[g][j] = (f32x4){0.f, 0.f, 0.f, 0.f};

#pragma unroll
    for (int kc = 0; kc < 4; ++kc) {
#pragma unroll
        for (int j = 0; j < 8; ++j) {
            BF8 b;
            b.q = *(const uint4*)&WfS[(size_t)((kc * 8 + j) * 64 + lane) * 8];
            acc[0][j] = __builtin_amdgcn_mfma_f32_16x16x32_bf16(a[0][kc].v, b.v, acc[0][j], 0, 0, 0);
            acc[1][j] = __builtin_amdgcn_mfma_f32_16x16x32_bf16(a[1][kc].v, b.v, acc[1][j], 0, 0, 0);
        }
    }

    float dv[2][4];
#pragma unroll
    for (int g = 0; g < 2; ++g)
#pragma unroll
        for (int r = 0; r < 4; ++r) {
            int row = wrow0 + g * 16 + kgrp * 4 + r;
            dv[g][r] = dinv[row < N ? row : (N - 1)];
        }

#pragma unroll
    for (int g = 0; g < 2; ++g) {
        char* sg = sw + g * 4096;
#pragma unroll
        for (int j = 0; j < 8; ++j) {
            int colb = (j * 16 + lrow) * 2;
#pragma unroll
            for (int r = 0; r < 4; ++r)
                *(ushort*)(sg + swz(kgrp * 4 + r, colb)) = f2bf(acc[g][j][r] * dv[g][r]);
        }
        size_t tb8 = (size_t)(wrow0 + g * 16) * DD;   // fp8: 128 B per row
#pragma unroll
        for (int i = 0; i < 4; ++i) {
            int row = i * 4 + srow;
            BF8 o;
            o.q = *(const uint4*)(sg + swz(row, scolb));
            uint2 w;
            w.x = f2fp8(bf2f(o.us[0])) | (f2fp8(bf2f(o.us[1])) << 8) |
                  (f2fp8(bf2f(o.us[2])) << 16) | (f2fp8(bf2f(o.us[3])) << 24);
            w.y = f2fp8(bf2f(o.us[4])) | (f2fp8(bf2f(o.us[5])) << 8) |
                  (f2fp8(bf2f(o.us[6])) << 16) | (f2fp8(bf2f(o.us[7])) << 24);
            int grow = wrow0 + g * 16 + row;
            if (grow < N) *(uint2*)&Y8[tb8 + i * 512 + lane * 8] = w;
        }
    }
}

// ---------------------------------------------------------------------------
// Fused CSR gather-agg (+self fold) + bias + BN + ReLU on pre-scaled fp8 hs.
// Degree-sorted (perm); 16 lanes/node (8B/lane); unroll-8 (r12 config —
// empirically best: high occupancy + 32 rows in flight per wave).
__global__ __launch_bounds__(256) void agg_kernel(
    const unsigned char* __restrict__ hs8, const int* __restrict__ row_ptr,
    const int* __restrict__ csr, const float* __restrict__ dinv,
    const int* __restrict__ perm,
    const float* __restrict__ bias, const float* __restrict__ gamma,
    const float* __restrict__ beta, const float* __restrict__ mean,
    const float* __restrict__ var, ushort* __restrict__ hout, int N) {
    int gid0 = (blockIdx.x * blockDim.x + threadIdx.x) >> 4;
    if (gid0 >= N) return;
    int gid = perm[gid0];
    int lane = threadIdx.x & 15;
    int c8 = lane * 8;                 // byte (= channel) offset

    float acc0[8], acc1[8], acc2[8], acc3[8];
#pragma unroll
    for (int i = 0; i < 8; ++i) { acc0[i] = 0.f; acc1[i] = 0.f; acc2[i] = 0.f; acc3[i] = 0.f; }
    // self term (pre-scaled)
    {
        uint2 sv = *(const uint2*)&hs8[(size_t)gid * DD + c8];
        acc8_fp8(sv.x, sv.y, acc0);
    }

    int s = row_ptr[gid], e = row_ptr[gid + 1];
    int p = s;
    for (; p + 8 <= e; p += 8) {
        int s0 = csr[p],     s1 = csr[p + 1], s2 = csr[p + 2], s3 = csr[p + 3];
        int s4 = csr[p + 4], s5 = csr[p + 5], s6 = csr[p + 6], s7 = csr[p + 7];
        uint2 r0 = *(const uint2*)&hs8[(size_t)s0 * DD + c8];
        uint2 r1 = *(const uint2*)&hs8[(size_t)s1 * DD + c8];
        uint2 r2 = *(const uint2*)&hs8[(size_t)s2 * DD + c8];
        uint2 r3 = *(const uint2*)&hs8[(size_t)s3 * DD + c8];
        uint2 r4 = *(const uint2*)&hs8[(size_t)s4 * DD + c8];
        uint2 r5 = *(const uint2*)&hs8[(size_t)s5 * DD + c8];
        uint2 r6 = *(const uint2*)&hs8[(size_t)s6 * DD + c8];
        uint2 r7 = *(const uint2*)&hs8[(size_t)s7 * DD + c8];
        acc8_fp8(r0.x, r0.y, acc0);
        acc8_fp8(r1.x, r1.y, acc1);
        acc8_fp8(r2.x, r2.y, acc2);
        acc8_fp8(r3.x, r3.y, acc3);
        acc8_fp8(r4.x, r4.y, acc0);
        acc8_fp8(r5.x, r5.y, acc1);
        acc8_fp8(r6.x, r6.y, acc2);
        acc8_fp8(r7.x, r7.y, acc3);
    }
    if (p + 4 <= e) {
        int s0 = csr[p], s1 = csr[p + 1], s2 = csr[p + 2], s3 = csr[p + 3];
        uint2 r0 = *(const uint2*)&hs8[(size_t)s0 * DD + c8];
        uint2 r1 = *(const uint2*)&hs8[(size_t)s1 * DD + c8];
        uint2 r2 = *(const uint2*)&hs8[(size_t)s2 * DD + c8];
        uint2 r3 = *(const uint2*)&hs8[(size_t)s3 * DD + c8];
        acc8_fp8(r0.x, r0.y, acc0);
        acc8_fp8(r1.x, r1.y, acc1);
        acc8_fp8(r2.x, r2.y, acc2);
        acc8_fp8(r3.x, r3.y, acc3);
        p += 4;
    }
    for (; p < e; ++p) {
        int s0 = csr[p];
        uint2 r0 = *(const uint2*)&hs8[(size_t)s0 * DD + c8];
        acc8_fp8(r0.x, r0.y, acc0);
    }
#pragma unroll
    for (int i = 0; i < 8; ++i) acc0[i] += (acc1[i] + acc2[i]) + acc3[i];

    float di = dinv[gid];
    int c = lane * 8;

    float bb[8], gg[8], be[8], mm[8], vv[8];
    *(float4*)&bb[0] = *(const float4*)&bias[c];  *(float4*)&bb[4] = *(const float4*)&bias[c + 4];
    *(float4*)&gg[0] = *(const float4*)&gamma[c]; *(float4*)&gg[4] = *(const float4*)&gamma[c + 4];
    *(float4*)&be[0] = *(const float4*)&beta[c];  *(float4*)&be[4] = *(const float4*)&beta[c + 4];
    *(float4*)&mm[0] = *(const float4*)&mean[c];  *(float4*)&mm[4] = *(const float4*)&mean[c + 4];
    *(float4*)&vv[0] = *(const float4*)&var[c];   *(float4*)&vv[4] = *(const float4*)&var[c + 4];

    BF8 o;
#pragma unroll
    for (int i = 0; i < 8; ++i) {
        float h = fmaf(di, acc0[i], bb[i]);
        float y = fmaxf(gg[i] * (h - mm[i]) * rsqrtf(vv[i] + 1e-5f) + be[i], 0.f);
        o.us[i] = f2bf(y);
    }
    *(uint4*)&hout[(size_t)gid * DD + c] = o.q;   // full 128B line write (no churn)
}

// ---------------------------------------------------------------------------
// out = log_softmax( (max_l h_l) @ lin_w + lin_b ). MFMA.
__global__ __launch_bounds__(256) void final_kernel(const ushort* __restrict__ hall,
                                                    size_t hstride, int L,
                                                    const ushort* __restrict__ Wpf,
                                                    const float* __restrict__ lb,
                                                    float* __restrict__ out, int N) {
    __shared__ char slab[4][4096];
    int wave = threadIdx.x >> 6, lane = threadIdx.x & 63;
    int row0 = blockIdx.x * 64 + wave * 16;
    int lrow = lane & 15, kgrp = lane >> 4;
    char* sw = slab[wave];
    size_t tbase = (size_t)row0 * DD;
    int srow = lane >> 4;
    int scolb = (lane & 15) * 16;

#pragma unroll
    for (int i = 0; i < 4; ++i) {
        const ushort* pp = &hall[tbase + i * 512 + lane * 8];
        uint4 m = *(const uint4*)pp;
        for (int l = 1; l < L; ++l)
            m = bfmax4(m, *(const uint4*)(pp + (size_t)l * hstride));
        int row = i * 4 + srow;
        *(uint4*)(sw + swz(row, scolb)) = m;
    }

    BF8 a[4];
#pragma unroll
    for (int kc = 0; kc < 4; ++kc)
        a[kc].q = *(const uint4*)(sw + swz(lrow, kgrp * 16 + kc * 64));

    f32x4 acc[3];
#pragma unroll
    for (int j = 0; j < 3; ++j) acc[j] = (f32x4){0.f, 0.f, 0.f, 0.f};
#pragma unroll
    for (int kc = 0; kc < 4; ++kc) {
#pragma unroll
        for (int j = 0; j < 3; ++j) {
            BF8 b;
            b.q = *(const uint4*)&Wpf[(size_t)((kc * 3 + j) * 64 + lane) * 8];
            acc[j] = __builtin_amdgcn_mfma_f32_16x16x32_bf16(a[kc].v, b.v, acc[j], 0, 0, 0);
        }
    }

    float lbv[3];
#pragma unroll
    for (int j = 0; j < 3; ++j) {
        int col = j * 16 + lrow;
        lbv[j] = (col < CC) ? lb[col] : 0.f;
    }
#pragma unroll
    for (int r = 0; r < 4; ++r) {
        int node = row0 + kgrp * 4 + r;
        float lg[3];
        float m = -1e30f;
#pragma unroll
        for (int j = 0; j < 3; ++j) {
            int col = j * 16 + lrow;
            float v = (col < CC) ? (acc[j][r] + lbv[j]) : -1e30f;
            lg[j] = v;
            m = fmaxf(m, v);
        }
        m = fmaxf(m, __shfl_xor(m, 1));
        m = fmaxf(m, __shfl_xor(m, 2));
        m = fmaxf(m, __shfl_xor(m, 4));
        m = fmaxf(m, __shfl_xor(m, 8));
        float s = 0.f;
#pragma unroll
        for (int j = 0; j < 3; ++j) {
            int col = j * 16 + lrow;
            if (col < CC) s += expf(lg[j] - m);
        }
        s += __shfl_xor(s, 1);
        s += __shfl_xor(s, 2);
        s += __shfl_xor(s, 4);
        s += __shfl_xor(s, 8);
        float lgs = logf(s);
        if (node < N) {
#pragma unroll
            for (int j = 0; j < 3; ++j) {
                int col = j * 16 + lrow;
                if (col < CC) out[(size_t)node * CC + col] = lg[j] - m - lgs;
            }
        }
    }
}

// ---------------------------------------------------------------------------
extern "C" void kernel_launch(void* const* d_in, const int* in_sizes, int n_in,
                              void* d_out, int out_size, void* d_ws, size_t ws_size,
                              hipStream_t stream) {
    const float* x      = (const float*)d_in[0];
    const void*  eidx   = d_in[1];
    const float* conv_w = (const float*)d_in[2];
    const float* conv_b = (const float*)d_in[3];
    const float* gamma  = (const float*)d_in[4];
    const float* beta   = (const float*)d_in[5];
    const float* mean   = (const float*)d_in[6];
    const float* var    = (const float*)d_in[7];
    const float* lin_w  = (const float*)d_in[8];
    const float* lin_b  = (const float*)d_in[9];
    float* out = (float*)d_out;

    const int N = in_sizes[0] / DD;          // 100000
    const int E = in_sizes[1] / 2;           // 800000
    const int L = in_sizes[3] / DD;          // 5
    const int NPAD2 = (N + 127) & ~127;      // 100096 (mm: 128 rows/block)
    const size_t hstride = (size_t)NPAD2 * DD;
    const int NB = (N + 1023) / 1024;        // scanA blocks
    const int nbk = (N + BSZ - 1) >> BSH;    // buckets (196)
    const int nbb = (E + EPB - 1) / EPB;     // bin blocks
    const int bcap = 2 * ((E + nbk - 1) / nbk) + 512;   // static bucket capacity
    const int totalW = L * 2048;
    const int prepn = totalW + 12 * 64;      // prep thread count (>= nbk, 64)

    char* p = (char*)d_ws;
    auto alloc = [&](size_t bytes) -> char* {
        char* r = p;
        p += (bytes + 255) & ~(size_t)255;
        return r;
    };
    unsigned char* xs8 = (unsigned char*)alloc(hstride);     // fp8 hs (per layer)
    ushort* hall   = (ushort*)alloc((size_t)L * hstride * 2);
    ushort* Wf     = (ushort*)alloc((size_t)L * DD * DD * 2);
    ushort* Wpf    = (ushort*)alloc((size_t)12 * 64 * 8 * 2);
    float*  dinv   = (float*)alloc((size_t)N * 4);
    int*    row_ptr= (int*)alloc((size_t)(N + 1) * 4);
    int*    cnt    = (int*)alloc((size_t)N * 4);
    int*    csr    = (int*)alloc((size_t)E * 4);
    int*    perm   = (int*)alloc((size_t)N * 4);
    unsigned* bins = (unsigned*)alloc((size_t)nbk * bcap * 4);
    int*    gcursor= (int*)alloc((size_t)nbk * 4);
    int*    blksum = (int*)alloc(128 * 4);
    int*    deghist= (int*)alloc(64 * 4);
    int*    degcur = (int*)alloc(64 * 4);
    int*    flag   = (int*)alloc(4);

    prep_kernel<<<(prepn + 255) / 256, 256, 0, stream>>>(
        (const unsigned*)eidx, flag, gcursor, deghist, nbk, bcap,
        conv_w, Wf, totalW, lin_w, Wpf);
    bin_kernel<<<nbb, 256, 0, stream>>>(eidx, flag, gcursor, bins, E, nbk, bcap);
    bcount_kernel<<<nbk, 256, 0, stream>>>(bins, gcursor, cnt, deghist, N, bcap);
    scanA_kernel<<<NB, 1024, 0, stream>>>(cnt, row_ptr, dinv, blksum, N);
    scanB_kernel<<<1, 128, 0, stream>>>(blksum, NB, deghist, degcur);
    scanCdeg_kernel<<<(N + 255) / 256, 256, 0, stream>>>(row_ptr, blksum, cnt, degcur, perm, N, E);
    bscatter_kernel<<<nbk, 256, 0, stream>>>(bins, row_ptr, gcursor, csr, N, bcap);

    for (int l = 0; l < L; ++l) {
        const ushort* Wl = Wf + (size_t)l * DD * DD;
        if (l == 0)
            mm_kernel<1><<<NPAD2 / 128, 256, 0, stream>>>(x, Wl, dinv, xs8, N);
        else
            mm_kernel<0><<<NPAD2 / 128, 256, 0, stream>>>(hall + (size_t)(l - 1) * hstride, Wl, dinv, xs8, N);
        ushort* hl = hall + (size_t)l * hstride;
        agg_kernel<<<(int)(((size_t)N * 16 + 255) / 256), 256, 0, stream>>>(
            xs8, row_ptr, csr, dinv, perm,
            conv_b + (size_t)l * DD, gamma + (size_t)l * DD, beta + (size_t)l * DD,
            mean + (size_t)l * DD, var + (size_t)l * DD, hl, N);
    }
    final_kernel<<<(N + 63) / 64, 256, 0, stream>>>(hall, hstride, L, Wpf, lin_b, out, N);
}